// Round 1
// baseline (28.624 us; speedup 1.0000x reference)
//
#include <hip/hip_runtime.h>
#include <math.h>

#define BATCH    4096
#define ND       13
#define NS       26
#define VOCAB    10000
#define NFIELD   39
#define KDIM     8
#define ROW      (NFIELD * KDIM)   // 312 floats per v row
#define NT       320               // 5 waves; threads 0..311 own one (f,k) slot
#define NWAVE    5

__global__ __launch_bounds__(NT) void ffm_kernel(
    const float* __restrict__ dense_x,   // (B, 13)
    const int*   __restrict__ sparse_x,  // (B, 26)
    const float* __restrict__ w0,        // (1,)
    const float* __restrict__ w,         // (260013, 1)
    const float* __restrict__ v,         // (260013, 39, 8)
    float*       __restrict__ out)       // (B, 1)
{
    const int b = blockIdx.x;
    const int t = threadIdx.x;

    __shared__ int   s_idx[NS];        // global row index into v / w
    __shared__ float s_dense[ND];
    __shared__ float s_part[NWAVE * KDIM];
    __shared__ float sq_part[NWAVE];

    if (t < NS) {
        s_idx[t] = ND + t * VOCAB + sparse_x[b * NS + t];
    }
    if (t >= 64 && t < 64 + ND) {
        s_dense[t - 64] = dense_x[b * ND + (t - 64)];
    }
    __syncthreads();

    // ---- accumulate field_f slot (f = t>>3, k = t&7) ----
    float acc = 0.f;
    if (t < ROW) {
        // dense part: v[:13] is 16 KB, L2-resident across all blocks
#pragma unroll
        for (int d = 0; d < ND; ++d)
            acc = fmaf(s_dense[d], v[d * ROW + t], acc);
        // sparse gathers: 26 independent coalesced 1248B row reads
#pragma unroll
        for (int j = 0; j < NS; ++j)
            acc += v[(size_t)s_idx[j] * ROW + t];
    }

    // ---- wave-level reductions ----
    // sum of squares over all slots (full 64-lane reduce)
    float sq = acc * acc;
#pragma unroll
    for (int m = 32; m >= 1; m >>= 1)
        sq += __shfl_xor(sq, m, 64);

    // per-k sum over f: within a wave, lanes with equal (lane&7) share k
    float sk = acc;
    sk += __shfl_xor(sk, 8, 64);
    sk += __shfl_xor(sk, 16, 64);
    sk += __shfl_xor(sk, 32, 64);

    const int wave = t >> 6;
    const int lane = t & 63;
    if (lane < KDIM) s_part[wave * KDIM + lane] = sk;
    if (lane == 0)   sq_part[wave] = sq;
    __syncthreads();

    // ---- epilogue on wave 0 ----
    if (t < 64) {
        float contrib = 0.f;
        if (t < KDIM) {                     // 0.5 * sum_k s_k^2
            float s = 0.f;
#pragma unroll
            for (int wv = 0; wv < NWAVE; ++wv) s += s_part[wv * KDIM + t];
            contrib += 0.5f * s * s;
        }
        if (t < NS)                          // sparse linear term (parallel gather)
            contrib += w[s_idx[t]];
        if (t >= 32 && t < 32 + ND)          // dense linear term
            contrib += s_dense[t - 32] * w[t - 32];
        if (t == 63) {                       // bias and -0.5 * sum f^2
            float ss = 0.f;
#pragma unroll
            for (int wv = 0; wv < NWAVE; ++wv) ss += sq_part[wv];
            contrib += w0[0] - 0.5f * ss;
        }
#pragma unroll
        for (int m = 32; m >= 1; m >>= 1)
            contrib += __shfl_xor(contrib, m, 64);
        if (t == 0)
            out[b] = 1.f / (1.f + expf(-contrib));
    }
}

extern "C" void kernel_launch(void* const* d_in, const int* in_sizes, int n_in,
                              void* d_out, int out_size, void* d_ws, size_t ws_size,
                              hipStream_t stream) {
    const float* dense_x  = (const float*)d_in[0];
    const int*   sparse_x = (const int*)d_in[1];
    const float* w0       = (const float*)d_in[2];
    const float* w        = (const float*)d_in[3];
    const float* v        = (const float*)d_in[4];
    float* out = (float*)d_out;

    hipLaunchKernelGGL(ffm_kernel, dim3(BATCH), dim3(NT), 0, stream,
                       dense_x, sparse_x, w0, w, v, out);
}